// Round 4
// baseline (1143.507 us; speedup 1.0000x reference)
//
#include <hip/hip_runtime.h>
#include <cmath>

#define DEV __device__ __forceinline__

constexpr int NA    = 32768;          // atoms
constexpr int M     = 12;             // neighbors
constexpr int ORIG  = 92;
constexpr int NBR   = 41;
constexpr int AF    = 64;
constexpr int C2    = 128;            // 2*AF
constexpr int HF    = 128;
constexpr int NCONV = 3;
constexpr int NM    = NA * M;         // 393216
constexpr int BB    = 1024;           // crystals
constexpr int TA    = 4;              // atoms per tile
constexpr int RT    = TA * M;         // 48 rows per tile
constexpr int NTILES = NA / TA;       // 8192
constexpr int GRID_CONV  = 2048;
constexpr int GRID_APPLY = 1024;
constexpr int WLD   = 132;            // W2t row stride (2-way banks only = free)
constexpr int ALD   = 44;             // A tile row stride

DEV float fsig(float x) { return __builtin_amdgcn_rcpf(1.f + __expf(-x)); }
DEV float fsp (float x) { return fmaxf(x, 0.f) + __logf(1.f + __expf(-fabsf(x))); }

DEV void fma4(float4& a, float s, const float4 w) {
    a.x = fmaf(s, w.x, a.x); a.y = fmaf(s, w.y, a.y);
    a.z = fmaf(s, w.z, a.z); a.w = fmaf(s, w.w, a.w);
}
DEV float comp4(const float4 v, int i) { return i == 0 ? v.x : i == 1 ? v.y : i == 2 ? v.z : v.w; }
DEV void add4(float4& a, const float4 b) { a.x += b.x; a.y += b.y; a.z += b.z; a.w += b.w; }
DEV void sqa4(float4& a, const float4 b) {
    a.x = fmaf(b.x, b.x, a.x); a.y = fmaf(b.y, b.y, a.y);
    a.z = fmaf(b.z, b.z, a.z); a.w = fmaf(b.w, b.w, a.w);
}
DEV float4 shxor(const float4 v, int m) {
    float4 r;
    r.x = __shfl_xor(v.x, m, 64); r.y = __shfl_xor(v.y, m, 64);
    r.z = __shfl_xor(v.z, m, 64); r.w = __shfl_xor(v.w, m, 64);
    return r;
}
DEV void bfly4(float4& v) {              // 4-way sum across lanes xor 16,32
    float4 t = shxor(v, 16); add4(v, t);
    t = shxor(v, 32); add4(v, t);
}
DEV unsigned bf16pair(float a, float b) {   // RNE pack: low=a, high=b
    unsigned ua = __float_as_uint(a), ub = __float_as_uint(b);
    ua += 0x7fffu + ((ua >> 16) & 1u);
    ub += 0x7fffu + ((ub >> 16) & 1u);
    return (ua >> 16) | (ub & 0xffff0000u);
}

// ---------------- embedding: x = atom_fea @ emb_W + emb_b ----------------
__global__ __launch_bounds__(256)
void embed_kernel(const float* __restrict__ atom_fea,
                  const float* __restrict__ Wm, const float* __restrict__ bm,
                  float* __restrict__ xo)
{
    __shared__ float af[4 * ORIG];
    const int a0 = blockIdx.x * 4, tid = threadIdx.x;
    for (int i = tid; i < 4 * ORIG; i += 256) af[i] = atom_fea[a0 * ORIG + i];
    __syncthreads();
    const int al = tid >> 6, c = tid & 63;
    float acc = bm[c];
    #pragma unroll 4
    for (int k = 0; k < ORIG; ++k) acc = fmaf(af[al * ORIG + k], Wm[k * AF + c], acc);
    xo[(a0 + al) * AF + c] = acc;
}

// ---------------- S = x@W[0:64] + b,  P = x@W[64:128]  (fused) ----------------
__global__ __launch_bounds__(256, 4)
void sp_kernel(const float* __restrict__ x,
               const float* __restrict__ W, const float* __restrict__ bias,
               float* __restrict__ S, float* __restrict__ P)
{
    __shared__ float xs[16][AF];
    const int a0 = blockIdx.x * 16, tid = threadIdx.x;
    {
        const int row = tid >> 4, c4 = (tid & 15) * 4;
        *(float4*)&xs[row][c4] = *(const float4*)(x + (size_t)(a0 + row) * AF + c4);
    }
    __syncthreads();
    const int cid = tid & 31, rid = tid >> 5;
    const int c0 = cid * 8, r0 = rid * 2;
    const bool isS = (c0 < 128);
    const int cc = c0 & 127;
    const float* Wb = W + (isS ? 0 : AF * C2) + cc;
    float* ob = (isS ? S : P);
    float4 a00, a01, a10, a11;
    if (isS) { a00 = *(const float4*)(bias + cc); a01 = *(const float4*)(bias + cc + 4); }
    else     { a00 = {0,0,0,0}; a01 = {0,0,0,0}; }
    a10 = a00; a11 = a01;
    for (int k = 0; k < AF; ++k) {
        const float4 w0 = *(const float4*)(Wb + k * C2);
        const float4 w1 = *(const float4*)(Wb + k * C2 + 4);
        const float x0 = xs[r0][k], x1 = xs[r0 + 1][k];
        fma4(a00, x0, w0); fma4(a01, x0, w1);
        fma4(a10, x1, w0); fma4(a11, x1, w1);
    }
    *(float4*)(ob + (size_t)(a0 + r0) * C2 + cc)     = a00;
    *(float4*)(ob + (size_t)(a0 + r0) * C2 + cc + 4) = a01;
    *(float4*)(ob + (size_t)(a0 + r0 + 1) * C2 + cc)     = a10;
    *(float4*)(ob + (size_t)(a0 + r0 + 1) * C2 + cc + 4) = a11;
}

// ---- pass 1: g = S[n] + P[idx] + nbr@W2; BN1 stats; optionally write g (bf16) ----
// Software-pipelined one tile ahead: accumulators init with S+P (so current
// gather regs die before the GEMM), next tile's idx/P/S/nbr issued pre-GEMM.
template<bool WG>
__global__ __launch_bounds__(256, 4)
void conv4_kernel(const float* __restrict__ nbr_fea,
                  const int* __restrict__ idx,
                  const float* __restrict__ W2,
                  const float* __restrict__ S,
                  const float* __restrict__ P,
                  float* __restrict__ P1s, float* __restrict__ P1q,
                  unsigned* __restrict__ gout)
{
    __shared__ float W2t[NBR * WLD];     // 21.6 KB
    __shared__ float sA[RT * ALD];       // 8.45 KB

    const int tid  = threadIdx.x;
    const int cid  = tid & 15;
    const int rid  = tid >> 4;
    const int cf   = cid * 4;            // filter col base; core col = cf + 64
    const int r0   = rid * 3;
    const int atom = tid >> 6;           // wave index == atom-in-tile

    for (int i = tid; i < NBR * 32; i += 256) {
        const int k = i >> 5, c4 = (i & 31) * 4;
        *(float4*)&W2t[k * WLD + c4] = *(const float4*)(W2 + k * C2 + c4);
    }

    // staging LDS offsets are tile-invariant: element e = tid + 256*i of a
    // contiguous 48x41 tile goes to sA[(e/41)*ALD + e%41]
    int soff[8];
    #pragma unroll
    for (int i = 0; i < 8; ++i) {
        const int e = tid + 256 * i;
        if (e < RT * NBR) {
            const int r = (int)(((unsigned)e * 102301u) >> 22);
            soff[i] = r * ALD + (e - r * NBR);
        } else soff[i] = -1;
    }

    const int stride = gridDim.x;
    int t = blockIdx.x;

    // ---- prologue: loads for first tile ----
    float nb[8];
    float4 pf0, pc0, pf1, pc1, pf2, pc2, svf, svc;
    {
        const int n0 = t * TA;
        const int j0 = idx[n0 * M + r0 + 0];
        const int j1 = idx[n0 * M + r0 + 1];
        const int j2 = idx[n0 * M + r0 + 2];
        const float* src = nbr_fea + (size_t)n0 * M * NBR;
        #pragma unroll
        for (int i = 0; i < 8; ++i) nb[i] = (soff[i] >= 0) ? src[tid + 256 * i] : 0.f;
        pf0 = *(const float4*)(P + (size_t)j0 * C2 + cf);
        pc0 = *(const float4*)(P + (size_t)j0 * C2 + 64 + cf);
        pf1 = *(const float4*)(P + (size_t)j1 * C2 + cf);
        pc1 = *(const float4*)(P + (size_t)j1 * C2 + 64 + cf);
        pf2 = *(const float4*)(P + (size_t)j2 * C2 + cf);
        pc2 = *(const float4*)(P + (size_t)j2 * C2 + 64 + cf);
        svf = *(const float4*)(S + (size_t)(n0 + atom) * C2 + cf);
        svc = *(const float4*)(S + (size_t)(n0 + atom) * C2 + 64 + cf);
    }

    float4 sum_f = {0,0,0,0}, sum_c = {0,0,0,0}, sq_f = {0,0,0,0}, sq_c = {0,0,0,0};

    for (; t < NTILES; t += stride) {
        const int n0 = t * TA;
        const int tn = t + stride;

        __syncthreads();                 // prev tile LDS fully consumed
        #pragma unroll
        for (int i = 0; i < 8; ++i) if (soff[i] >= 0) sA[soff[i]] = nb[i];
        __syncthreads();

        // accumulators start at S + P[idx] (frees current gather regs now)
        float4 ef0 = svf, ec0 = svc, ef1 = svf, ec1 = svc, ef2 = svf, ec2 = svc;
        add4(ef0, pf0); add4(ec0, pc0);
        add4(ef1, pf1); add4(ec1, pc1);
        add4(ef2, pf2); add4(ec2, pc2);

        // ---- issue next tile's loads (latency hides behind the GEMM) ----
        if (tn < NTILES) {
            const int m0 = tn * TA;
            const float* srcn = nbr_fea + (size_t)m0 * M * NBR;
            #pragma unroll
            for (int i = 0; i < 8; ++i) nb[i] = (soff[i] >= 0) ? srcn[tid + 256 * i] : 0.f;
            const int j0 = idx[m0 * M + r0 + 0];
            const int j1 = idx[m0 * M + r0 + 1];
            const int j2 = idx[m0 * M + r0 + 2];
            pf0 = *(const float4*)(P + (size_t)j0 * C2 + cf);
            pc0 = *(const float4*)(P + (size_t)j0 * C2 + 64 + cf);
            pf1 = *(const float4*)(P + (size_t)j1 * C2 + cf);
            pc1 = *(const float4*)(P + (size_t)j1 * C2 + 64 + cf);
            pf2 = *(const float4*)(P + (size_t)j2 * C2 + cf);
            pc2 = *(const float4*)(P + (size_t)j2 * C2 + 64 + cf);
            svf = *(const float4*)(S + (size_t)(m0 + atom) * C2 + cf);
            svc = *(const float4*)(S + (size_t)(m0 + atom) * C2 + 64 + cf);
        }

        // ---- E-GEMM: += nbr @ W2 for 3 rows x (4+4) cols ----
        const float4* A0 = (const float4*)(sA + (r0 + 0) * ALD);
        const float4* A1 = (const float4*)(sA + (r0 + 1) * ALD);
        const float4* A2 = (const float4*)(sA + (r0 + 2) * ALD);
        #pragma unroll 2
        for (int k4 = 0; k4 < 10; ++k4) {
            const float4 a0 = A0[k4], a1 = A1[k4], a2 = A2[k4];
            #pragma unroll
            for (int kk = 0; kk < 4; ++kk) {
                const int k = 4 * k4 + kk;
                const float4 wf = *(const float4*)(W2t + k * WLD + cf);
                const float4 wc = *(const float4*)(W2t + k * WLD + 64 + cf);
                fma4(ef0, comp4(a0, kk), wf); fma4(ec0, comp4(a0, kk), wc);
                fma4(ef1, comp4(a1, kk), wf); fma4(ec1, comp4(a1, kk), wc);
                fma4(ef2, comp4(a2, kk), wf); fma4(ec2, comp4(a2, kk), wc);
            }
        }
        {
            const float4 wf = *(const float4*)(W2t + 40 * WLD + cf);
            const float4 wc = *(const float4*)(W2t + 40 * WLD + 64 + cf);
            const float a0s = sA[(r0 + 0) * ALD + 40];
            const float a1s = sA[(r0 + 1) * ALD + 40];
            const float a2s = sA[(r0 + 2) * ALD + 40];
            fma4(ef0, a0s, wf); fma4(ec0, a0s, wc);
            fma4(ef1, a1s, wf); fma4(ec1, a1s, wc);
            fma4(ef2, a2s, wf); fma4(ec2, a2s, wc);
        }

        // ---- stats + g write ----
        add4(sum_f, ef0); add4(sum_f, ef1); add4(sum_f, ef2);
        add4(sum_c, ec0); add4(sum_c, ec1); add4(sum_c, ec2);
        sqa4(sq_f, ef0);  sqa4(sq_f, ef1);  sqa4(sq_f, ef2);
        sqa4(sq_c, ec0);  sqa4(sq_c, ec1);  sqa4(sq_c, ec2);

        if (WG) {
            const size_t row0 = (size_t)(n0 * M + r0) * 64 + 2 * cid;
            uint2 w;
            w.x = bf16pair(ef0.x, ef0.y); w.y = bf16pair(ef0.z, ef0.w);
            *(uint2*)(gout + row0) = w;
            w.x = bf16pair(ec0.x, ec0.y); w.y = bf16pair(ec0.z, ec0.w);
            *(uint2*)(gout + row0 + 32) = w;
            w.x = bf16pair(ef1.x, ef1.y); w.y = bf16pair(ef1.z, ef1.w);
            *(uint2*)(gout + row0 + 64) = w;
            w.x = bf16pair(ec1.x, ec1.y); w.y = bf16pair(ec1.z, ec1.w);
            *(uint2*)(gout + row0 + 96) = w;
            w.x = bf16pair(ef2.x, ef2.y); w.y = bf16pair(ef2.z, ef2.w);
            *(uint2*)(gout + row0 + 128) = w;
            w.x = bf16pair(ec2.x, ec2.y); w.y = bf16pair(ec2.z, ec2.w);
            *(uint2*)(gout + row0 + 160) = w;
        }
    }

    // block-level reduce of per-thread stats
    bfly4(sum_f); bfly4(sum_c); bfly4(sq_f); bfly4(sq_c);
    __syncthreads();                     // sA free (all tiles done)
    if ((tid & 48) == 0) {
        *(float4*)&sA[atom * C2 + cf]            = sum_f;
        *(float4*)&sA[atom * C2 + 64 + cf]       = sum_c;
        *(float4*)&sA[512 + atom * C2 + cf]      = sq_f;
        *(float4*)&sA[512 + atom * C2 + 64 + cf] = sq_c;
    }
    __syncthreads();
    if (tid < C2) {
        P1s[blockIdx.x * C2 + tid] = sA[tid] + sA[C2 + tid] + sA[2 * C2 + tid] + sA[3 * C2 + tid];
        P1q[blockIdx.x * C2 + tid] = sA[512 + tid] + sA[512 + C2 + tid]
                                   + sA[512 + 2 * C2 + tid] + sA[512 + 3 * C2 + tid];
    }
}

// ---- pass 2 (fast path): read g (bf16), BN1, gate, reduce over M; BN2 partials ----
__global__ __launch_bounds__(256)
void apply_kernel(const unsigned* __restrict__ g,
                  const float* __restrict__ ss1,
                  float* __restrict__ summed,
                  float* __restrict__ P2s, float* __restrict__ P2q)
{
    const int tid = threadIdx.x;
    const int al  = tid >> 5;            // 0..7 atoms per group
    const int c2  = tid & 31;            // col pair
    const int cA  = 2 * c2;
    const float2 scf = *(const float2*)(ss1 + cA);
    const float2 scc = *(const float2*)(ss1 + 64 + cA);
    const float2 shf = *(const float2*)(ss1 + C2 + cA);
    const float2 shc = *(const float2*)(ss1 + C2 + 64 + cA);
    float2 ts = {0.f, 0.f}, tq = {0.f, 0.f};

    for (int grp = blockIdx.x; grp < NA / 8; grp += gridDim.x) {
        const int a = grp * 8 + al;
        const unsigned* gr = g + (size_t)a * M * 64 + c2;
        float2 acc = {0.f, 0.f};
        #pragma unroll
        for (int m = 0; m < M; ++m) {
            const unsigned uf = gr[m * 64];
            const unsigned us = gr[m * 64 + 32];
            const float f0 = __uint_as_float(uf << 16);
            const float f1 = __uint_as_float(uf & 0xffff0000u);
            const float s0 = __uint_as_float(us << 16);
            const float s1 = __uint_as_float(us & 0xffff0000u);
            acc.x = fmaf(fsig(fmaf(f0, scf.x, shf.x)), fsp(fmaf(s0, scc.x, shc.x)), acc.x);
            acc.y = fmaf(fsig(fmaf(f1, scf.y, shf.y)), fsp(fmaf(s1, scc.y, shc.y)), acc.y);
        }
        *(float2*)(summed + (size_t)a * AF + cA) = acc;
        ts.x += acc.x; ts.y += acc.y;
        tq.x = fmaf(acc.x, acc.x, tq.x); tq.y = fmaf(acc.y, acc.y, tq.y);
    }

    __shared__ float2 rs[8][32], rq[8][32];
    rs[al][c2] = ts; rq[al][c2] = tq;
    __syncthreads();
    if (tid < 32) {
        float2 s = rs[0][tid], q = rq[0][tid];
        #pragma unroll
        for (int a = 1; a < 8; ++a) {
            s.x += rs[a][tid].x; s.y += rs[a][tid].y;
            q.x += rq[a][tid].x; q.y += rq[a][tid].y;
        }
        *(float2*)(P2s + blockIdx.x * AF + 2 * tid) = s;
        *(float2*)(P2q + blockIdx.x * AF + 2 * tid) = q;
    }
}

// ---- pass 2 (fallback): recompute g and apply (Round-3 structure) ----
__global__ __launch_bounds__(256, 4)
void conv_apply_kernel(const float* __restrict__ nbr_fea,
                       const int* __restrict__ idx,
                       const float* __restrict__ W2,
                       const float* __restrict__ S,
                       const float* __restrict__ P,
                       const float* __restrict__ ss1,
                       float* __restrict__ summed)
{
    __shared__ float W2t[NBR * WLD];
    __shared__ float sA[RT * ALD];

    const int tid  = threadIdx.x;
    const int cid  = tid & 15;
    const int rid  = tid >> 4;
    const int cf   = cid * 4;
    const int r0   = rid * 3;
    const int atom = tid >> 6;

    for (int i = tid; i < NBR * 32; i += 256) {
        const int k = i >> 5, c4 = (i & 31) * 4;
        *(float4*)&W2t[k * WLD + c4] = *(const float4*)(W2 + k * C2 + c4);
    }
    const float4 scf = *(const float4*)(ss1 + cf);
    const float4 scc = *(const float4*)(ss1 + 64 + cf);
    const float4 shf = *(const float4*)(ss1 + C2 + cf);
    const float4 shc = *(const float4*)(ss1 + C2 + 64 + cf);

    for (int t = blockIdx.x; t < NTILES; t += gridDim.x) {
        const int n0 = t * TA;
        const int j0 = idx[n0 * M + r0 + 0];
        const int j1 = idx[n0 * M + r0 + 1];
        const int j2 = idx[n0 * M + r0 + 2];
        const float4 p0f = *(const float4*)(P + (size_t)j0 * C2 + cf);
        const float4 p0c = *(const float4*)(P + (size_t)j0 * C2 + 64 + cf);
        const float4 p1f = *(const float4*)(P + (size_t)j1 * C2 + cf);
        const float4 p1c = *(const float4*)(P + (size_t)j1 * C2 + 64 + cf);
        const float4 p2f = *(const float4*)(P + (size_t)j2 * C2 + cf);
        const float4 p2c = *(const float4*)(P + (size_t)j2 * C2 + 64 + cf);
        const float4 svf = *(const float4*)(S + (size_t)(n0 + atom) * C2 + cf);
        const float4 svc = *(const float4*)(S + (size_t)(n0 + atom) * C2 + 64 + cf);

        __syncthreads();
        {
            const float* src = nbr_fea + (size_t)n0 * M * NBR;
            for (int i = tid; i < RT * NBR; i += 256) {
                const int r = (int)(((unsigned)i * 102301u) >> 22);
                sA[r * ALD + (i - r * NBR)] = src[i];
            }
        }
        __syncthreads();

        float4 ef0 = svf, ec0 = svc, ef1 = svf, ec1 = svc, ef2 = svf, ec2 = svc;
        add4(ef0, p0f); add4(ec0, p0c);
        add4(ef1, p1f); add4(ec1, p1c);
        add4(ef2, p2f); add4(ec2, p2c);

        const float4* A0 = (const float4*)(sA + (r0 + 0) * ALD);
        const float4* A1 = (const float4*)(sA + (r0 + 1) * ALD);
        const float4* A2 = (const float4*)(sA + (r0 + 2) * ALD);
        #pragma unroll 2
        for (int k4 = 0; k4 < 10; ++k4) {
            const float4 a0 = A0[k4], a1 = A1[k4], a2 = A2[k4];
            #pragma unroll
            for (int kk = 0; kk < 4; ++kk) {
                const int k = 4 * k4 + kk;
                const float4 wf = *(const float4*)(W2t + k * WLD + cf);
                const float4 wc = *(const float4*)(W2t + k * WLD + 64 + cf);
                fma4(ef0, comp4(a0, kk), wf); fma4(ec0, comp4(a0, kk), wc);
                fma4(ef1, comp4(a1, kk), wf); fma4(ec1, comp4(a1, kk), wc);
                fma4(ef2, comp4(a2, kk), wf); fma4(ec2, comp4(a2, kk), wc);
            }
        }
        {
            const float4 wf = *(const float4*)(W2t + 40 * WLD + cf);
            const float4 wc = *(const float4*)(W2t + 40 * WLD + 64 + cf);
            const float a0s = sA[(r0 + 0) * ALD + 40];
            const float a1s = sA[(r0 + 1) * ALD + 40];
            const float a2s = sA[(r0 + 2) * ALD + 40];
            fma4(ef0, a0s, wf); fma4(ec0, a0s, wc);
            fma4(ef1, a1s, wf); fma4(ec1, a1s, wc);
            fma4(ef2, a2s, wf); fma4(ec2, a2s, wc);
        }

        float4 part = {0,0,0,0};
        #pragma unroll
        for (int j = 0; j < 3; ++j) {
            const float4 gf = (j == 0) ? ef0 : (j == 1) ? ef1 : ef2;
            const float4 gc = (j == 0) ? ec0 : (j == 1) ? ec1 : ec2;
            float4 nf, nc;
            nf.x = fmaf(gf.x, scf.x, shf.x); nf.y = fmaf(gf.y, scf.y, shf.y);
            nf.z = fmaf(gf.z, scf.z, shf.z); nf.w = fmaf(gf.w, scf.w, shf.w);
            nc.x = fmaf(gc.x, scc.x, shc.x); nc.y = fmaf(gc.y, scc.y, shc.y);
            nc.z = fmaf(gc.z, scc.z, shc.z); nc.w = fmaf(gc.w, scc.w, shc.w);
            part.x = fmaf(fsig(nf.x), fsp(nc.x), part.x);
            part.y = fmaf(fsig(nf.y), fsp(nc.y), part.y);
            part.z = fmaf(fsig(nf.z), fsp(nc.z), part.z);
            part.w = fmaf(fsig(nf.w), fsp(nc.w), part.w);
        }
        bfly4(part);
        if ((tid & 48) == 0)
            *(float4*)(summed + (size_t)(n0 + atom) * AF + cf) = part;
    }
}

// ---------------- BN stats finalize ----------------
__global__ __launch_bounds__(256)
void bn_finalize(const float* __restrict__ Ps, const float* __restrict__ Pq,
                 int npart, int C, float invn,
                 const float* __restrict__ gamma, const float* __restrict__ beta,
                 float* __restrict__ ss)
{
    __shared__ float sd[256];
    const int c = blockIdx.x, tid = threadIdx.x;
    float s = 0.f;
    for (int j = tid; j < npart; j += 256) s += Ps[j * C + c];
    sd[tid] = s; __syncthreads();
    for (int st = 128; st > 0; st >>= 1) { if (tid < st) sd[tid] += sd[tid + st]; __syncthreads(); }
    const float total = sd[0];
    __syncthreads();
    float q = 0.f;
    for (int j = tid; j < npart; j += 256) q += Pq[j * C + c];
    sd[tid] = q; __syncthreads();
    for (int st = 128; st > 0; st >>= 1) { if (tid < st) sd[tid] += sd[tid + st]; __syncthreads(); }
    if (tid == 0) {
        const float mean = total * invn;
        const float var  = sd[0] * invn - mean * mean;
        const float scl  = gamma[c] * rsqrtf(var + 1e-5f);
        ss[c]     = scl;
        ss[C + c] = beta[c] - mean * scl;
    }
}

// ---------------- stats over summed (fallback path only) ----------------
__global__ __launch_bounds__(256)
void stats2_partial(const float* __restrict__ summed, float* __restrict__ Ps, float* __restrict__ Pq)
{
    __shared__ float sp[4][64], sq[4][64];
    const int c = threadIdx.x & 63, rg = threadIdx.x >> 6;
    float s = 0.f, q = 0.f;
    const int base = blockIdx.x * 512;
    for (int r = rg; r < 512; r += 4) {
        const float v = summed[(size_t)(base + r) * AF + c];
        s += v; q += v * v;
    }
    sp[rg][c] = s; sq[rg][c] = q; __syncthreads();
    if (threadIdx.x < 64) {
        Ps[blockIdx.x * AF + c] = sp[0][c] + sp[1][c] + sp[2][c] + sp[3][c];
        Pq[blockIdx.x * AF + c] = sq[0][c] + sq[1][c] + sq[2][c] + sq[3][c];
    }
}

// ---------------- x_out = softplus(x_in + bn2(summed)) ----------------
__global__ __launch_bounds__(256)
void update_x_kernel(const float* __restrict__ xin, const float* __restrict__ summed,
                     const float* __restrict__ ss2, float* __restrict__ xout)
{
    const int gid = blockIdx.x * 256 + threadIdx.x;
    const int base = gid * 4;
    const int c0 = base & 63;
    const float4 xi = *(const float4*)(xin + base);
    const float4 sm = *(const float4*)(summed + base);
    const float4 sc = *(const float4*)(ss2 + c0);
    const float4 sh = *(const float4*)(ss2 + AF + c0);
    float4 o;
    o.x = fsp(xi.x + fmaf(sm.x, sc.x, sh.x));
    o.y = fsp(xi.y + fmaf(sm.y, sc.y, sh.y));
    o.z = fsp(xi.z + fmaf(sm.z, sc.z, sh.z));
    o.w = fsp(xi.w + fmaf(sm.w, sc.w, sh.w));
    *(float4*)(xout + base) = o;
}

// ---------------- pool + MLP head ----------------
__global__ __launch_bounds__(128)
void head_kernel(const float* __restrict__ x,
                 const float* __restrict__ fc1W, const float* __restrict__ fc1b,
                 const float* __restrict__ fc2W, const float* __restrict__ fc2b,
                 const float* __restrict__ outW, const float* __restrict__ outb,
                 float* __restrict__ out)
{
    __shared__ float l0[AF], l1[HF], rr[2];
    const int b = blockIdx.x, tid = threadIdx.x;
    if (tid < AF) {
        float s = 0.f;
        #pragma unroll 4
        for (int a = 0; a < 32; ++a) s += x[(size_t)(b * 32 + a) * AF + tid];
        l0[tid] = fsp(s * (1.f / 32.f));
    }
    __syncthreads();
    float acc = fc1b[tid];
    #pragma unroll 4
    for (int k = 0; k < AF; ++k) acc = fmaf(l0[k], fc1W[k * HF + tid], acc);
    l1[tid] = fsp(acc);
    __syncthreads();
    acc = fc2b[tid];
    #pragma unroll 4
    for (int k = 0; k < HF; ++k) acc = fmaf(l1[k], fc2W[k * HF + tid], acc);
    float v = fsp(acc) * outW[tid];
    #pragma unroll
    for (int off = 32; off > 0; off >>= 1) v += __shfl_down(v, off, 64);
    if ((tid & 63) == 0) rr[tid >> 6] = v;
    __syncthreads();
    if (tid == 0) out[b] = rr[0] + rr[1] + outb[0];
}

extern "C" void kernel_launch(void* const* d_in, const int* in_sizes, int n_in,
                              void* d_out, int out_size, void* d_ws, size_t ws_size,
                              hipStream_t stream)
{
    const float* atom_fea = (const float*)d_in[0];
    const float* nbr_fea  = (const float*)d_in[1];
    const int*   nbr_idx  = (const int*)d_in[2];
    const float* emb_W  = (const float*)d_in[4];
    const float* emb_b  = (const float*)d_in[5];
    const float* conv_W = (const float*)d_in[6];
    const float* conv_b = (const float*)d_in[7];
    const float* bn1_g  = (const float*)d_in[8];
    const float* bn1_b  = (const float*)d_in[9];
    const float* bn2_g  = (const float*)d_in[10];
    const float* bn2_b  = (const float*)d_in[11];
    const float* fc1W   = (const float*)d_in[12];
    const float* fc1b   = (const float*)d_in[13];
    const float* fc2W   = (const float*)d_in[14];
    const float* fc2b   = (const float*)d_in[15];
    const float* outW   = (const float*)d_in[16];
    const float* outb   = (const float*)d_in[17];
    float* out = (float*)d_out;
    float* ws  = (float*)d_ws;

    float* x_a    = ws;
    float* x_b    = x_a + (size_t)NA * AF;
    float* Sbuf   = x_b + (size_t)NA * AF;
    float* Pbuf   = Sbuf + (size_t)NA * C2;
    float* summed = Pbuf + (size_t)NA * C2;
    float* P1s    = summed + (size_t)NA * AF;
    float* P1q    = P1s + GRID_CONV * C2;
    float* P2s    = P1q + GRID_CONV * C2;
    float* P2q    = P2s + GRID_APPLY * AF;
    float* ss1    = P2q + GRID_APPLY * AF;
    float* ss2    = ss1 + 2 * C2;
    float* endf   = ss2 + 2 * AF;
    unsigned* gbuf = (unsigned*)endf;                       // NM x 64 uints (bf16 pairs)
    const size_t need = ((size_t)(endf - ws)) * 4 + (size_t)NM * 64 * 4;
    const bool use_g = (ws_size >= need);

    embed_kernel<<<NA / 4, 256, 0, stream>>>(atom_fea, emb_W, emb_b, x_a);

    float* xin = x_a; float* xout = x_b;
    for (int l = 0; l < NCONV; ++l) {
        const float* Wl = conv_W + (size_t)l * (2 * AF + NBR) * C2;
        const float* bl = conv_b + (size_t)l * C2;
        const float* W2 = Wl + C2 * C2;

        sp_kernel<<<NA / 16, 256, 0, stream>>>(xin, Wl, bl, Sbuf, Pbuf);
        if (use_g) {
            conv4_kernel<true><<<GRID_CONV, 256, 0, stream>>>(nbr_fea, nbr_idx, W2, Sbuf, Pbuf,
                                                              P1s, P1q, gbuf);
            bn_finalize<<<C2, 256, 0, stream>>>(P1s, P1q, GRID_CONV, C2, 1.f / (float)NM,
                                                bn1_g + l * C2, bn1_b + l * C2, ss1);
            apply_kernel<<<GRID_APPLY, 256, 0, stream>>>(gbuf, ss1, summed, P2s, P2q);
            bn_finalize<<<AF, 256, 0, stream>>>(P2s, P2q, GRID_APPLY, AF, 1.f / (float)NA,
                                                bn2_g + l * AF, bn2_b + l * AF, ss2);
        } else {
            conv4_kernel<false><<<GRID_CONV, 256, 0, stream>>>(nbr_fea, nbr_idx, W2, Sbuf, Pbuf,
                                                               P1s, P1q, nullptr);
            bn_finalize<<<C2, 256, 0, stream>>>(P1s, P1q, GRID_CONV, C2, 1.f / (float)NM,
                                                bn1_g + l * C2, bn1_b + l * C2, ss1);
            conv_apply_kernel<<<GRID_CONV, 256, 0, stream>>>(nbr_fea, nbr_idx, W2, Sbuf, Pbuf,
                                                             ss1, summed);
            stats2_partial<<<64, 256, 0, stream>>>(summed, P2s, P2q);
            bn_finalize<<<AF, 256, 0, stream>>>(P2s, P2q, 64, AF, 1.f / (float)NA,
                                                bn2_g + l * AF, bn2_b + l * AF, ss2);
        }
        update_x_kernel<<<NA * AF / 4 / 256, 256, 0, stream>>>(xin, summed, ss2, xout);
        float* tmp = xin; xin = xout; xout = tmp;
    }
    head_kernel<<<BB, 128, 0, stream>>>(xin, fc1W, fc1b, fc2W, fc2b, outW, outb, out);
}